// Round 3
// baseline (351.341 us; speedup 1.0000x reference)
//
#include <hip/hip_runtime.h>

// GRU: B=2048, T=1024, I=1, H=20, fused with output projection.
// TWO sequences per wave (grid 1024 x 64): two independent serial chains
// statically interleaved in one instruction stream so the scheduler hides
// each chain's latency (bpermute ~100cy, dot chain ~60cy) under the other's
// issue. Lane layout per sequence (same as R2, which passed):
//   lanes  0..19 : r rows   (weights pre-scaled by log2e)
//   lanes 20..39 : z rows   (log2e)
//   lanes 40..59 : n rows   (2*log2e); lane 40+j owns h[j]
//   lane  60     : W_out row -> y from the same shared dot
// h-broadcast: 20x v_readlane; r,z -> n transport: 2x ds_bpermute (LDS pipe).
// y: lane 60 ds_writes a 64-slot LDS ring per seq; coalesced flush / 64 steps.

#define LOG2E 1.44269504088896340736f

static __device__ __forceinline__ float fast_rcp(float x) {
    return __builtin_amdgcn_rcpf(x);
}
static __device__ __forceinline__ float fast_exp2(float x) {
    float r;
    asm("v_exp_f32 %0, %1" : "=v"(r) : "v"(x));
    return r;
}
static __device__ __forceinline__ float lane_bcast(float v, int srclane) {
    return __int_as_float(__builtin_amdgcn_readlane(__float_as_int(v), srclane));
}

// One GRU step for one sequence. Returns the shared pre-activation dot
// (on lane 60 this equals y_{i-1}); updates hcur in place.
static __device__ __forceinline__ float gru_step(
    float x, float& hcur, const float* __restrict__ w,
    float wih_rz, float wih_full, float bihv, float cbias,
    int sr, int sz)
{
    float hs[20];
    #pragma unroll
    for (int k = 0; k < 20; ++k) hs[k] = lane_bcast(hcur, 40 + k);

    float acc  = fmaf(x, wih_rz, cbias);
    float gi   = fmaf(x, wih_full, bihv);
    float acc2 = 0.f;
    #pragma unroll
    for (int k = 0; k < 10; ++k)  acc  = fmaf(hs[k], w[k], acc);
    #pragma unroll
    for (int k = 10; k < 20; ++k) acc2 = fmaf(hs[k], w[k], acc2);
    acc += acc2;

    float s  = fast_rcp(1.f + fast_exp2(-acc));   // sigmoid (r,z lanes)
    float rj = __shfl(s, sr, 64);
    float zj = __shfl(s, sz, 64);

    float npre = fmaf(rj, acc, gi);               // pre-scaled by 2*log2e
    float nval = 1.f - 2.f * fast_rcp(1.f + fast_exp2(npre));
    hcur = fmaf(zj, hcur - nval, nval);
    return acc;
}

static __device__ __forceinline__ float tail_dot(
    float hcur, const float* __restrict__ w, float cbias)
{
    float hs[20];
    #pragma unroll
    for (int k = 0; k < 20; ++k) hs[k] = lane_bcast(hcur, 40 + k);
    float acc  = cbias;
    float acc2 = 0.f;
    #pragma unroll
    for (int k = 0; k < 10; ++k)  acc  = fmaf(hs[k], w[k], acc);
    #pragma unroll
    for (int k = 10; k < 20; ++k) acc2 = fmaf(hs[k], w[k], acc2);
    return acc + acc2;
}

__global__ __launch_bounds__(64) void gru_fused2(
    const float* __restrict__ X,     // [B, T, 1]
    const float* __restrict__ H0,    // [1, B, 20]
    const float* __restrict__ Wih,   // [60, 1]
    const float* __restrict__ Whh,   // [60, 20]
    const float* __restrict__ Bih,   // [60]
    const float* __restrict__ Bhh,   // [60]
    const float* __restrict__ Wout,  // [1, 20]
    const float* __restrict__ Bout,  // [1]
    float* __restrict__ Y,           // [B*T]
    float* __restrict__ Hlast)       // [B, 20]
{
    constexpr int T = 1024;
    constexpr int H = 20;
    const int b0   = blockIdx.x * 2;
    const int b1   = b0 + 1;
    const int lane = threadIdx.x;

    __shared__ float lds[192];   // 0..63: ring A; 64..127: ring B; 128..191: junk

    // ---- per-lane constants (shared by both sequences) ----
    float w[H];
    float wih_full = 0.f, bihv = 0.f, cbias = 0.f, wih_rz = 0.f;
    if (lane < 60) {
        const float sc = (lane < 40) ? LOG2E : 2.0f * LOG2E;
        #pragma unroll
        for (int k = 0; k < H; ++k) w[k] = Whh[lane * H + k] * sc;
        wih_full = Wih[lane];
        bihv     = Bih[lane];
        if (lane < 40) {
            cbias  = (Bih[lane] + Bhh[lane]) * sc;
            wih_rz = wih_full * sc;
        } else {
            cbias     = Bhh[lane] * sc;
            wih_full *= sc;
            bihv     *= sc;
        }
    } else if (lane == 60) {
        #pragma unroll
        for (int k = 0; k < H; ++k) w[k] = Wout[k];   // unscaled
        cbias = Bout[0];
    } else {
        #pragma unroll
        for (int k = 0; k < H; ++k) w[k] = 0.f;
    }

    const bool is_n = (lane >= 40) && (lane < 60);
    const int  jn   = lane - 40;
    const int  sr   = is_n ? jn          : lane;   // bpermute src (loop-invariant)
    const int  sz   = is_n ? (lane - 20) : lane;

    float hA = H0[b0 * H + (is_n ? jn : 0)];
    float hB = H0[b1 * H + (is_n ? jn : 0)];

    const float4* X4A = (const float4*)(X + (size_t)b0 * T);
    const float4* X4B = (const float4*)(X + (size_t)b1 * T);
    float4 xqA = X4A[0], xqB = X4B[0];

    float* YA = Y + (size_t)b0 * T;
    float* YB = Y + (size_t)b1 * T;

    for (int q = 0; q < T / 4; ++q) {
        const int qn = (q < T / 4 - 1) ? (q + 1) : (T / 4 - 1);
        float4 xnA = X4A[qn];
        float4 xnB = X4B[qn];
        #pragma unroll
        for (int u = 0; u < 4; ++u) {
            const int   i  = 4 * q + u;
            const float xA = (u == 0) ? xqA.x : (u == 1) ? xqA.y
                           : (u == 2) ? xqA.z : xqA.w;
            const float xB = (u == 0) ? xqB.x : (u == 1) ? xqB.y
                           : (u == 2) ? xqB.z : xqB.w;

            // flush 64 y-values per seq every 64 steps (i == 65, 129, ...)
            if (u == 1 && (q & 15) == 0 && q > 0) {
                YA[(4 * q - 64) + lane] = lds[lane];
                YB[(4 * q - 64) + lane] = lds[64 + lane];
            }

            // two independent chains — scheduler interleaves them
            float accA = gru_step(xA, hA, w, wih_rz, wih_full, bihv, cbias, sr, sz);
            float accB = gru_step(xB, hB, w, wih_rz, wih_full, bihv, cbias, sr, sz);

            // y rings (lane 60 -> ring slot; everyone else -> junk region)
            const int slot = (i + 63) & 63;                  // wave-uniform
            lds[(lane == 60) ? slot        : (128 + lane)] = accA;
            lds[(lane == 60) ? (64 + slot) : (128 + lane)] = accB;
        }
        xqA = xnA;
        xqB = xnB;
    }

    // tail: y_{T-1} = W_out . h_T + b_out for both sequences
    {
        float accA = tail_dot(hA, w, cbias);
        float accB = tail_dot(hB, w, cbias);
        lds[(lane == 60) ? 63  : (128 + lane)] = accA;
        lds[(lane == 60) ? 127 : (128 + lane)] = accB;
        YA[(T - 64) + lane] = lds[lane];
        YB[(T - 64) + lane] = lds[64 + lane];
    }

    if (is_n) {
        Hlast[b0 * H + jn] = hA;
        Hlast[b1 * H + jn] = hB;
    }
}

extern "C" void kernel_launch(void* const* d_in, const int* in_sizes, int n_in,
                              void* d_out, int out_size, void* d_ws, size_t ws_size,
                              hipStream_t stream) {
    const float* X    = (const float*)d_in[0];
    const float* H0   = (const float*)d_in[1];
    const float* Wih  = (const float*)d_in[2];
    const float* Whh  = (const float*)d_in[3];
    const float* Bih  = (const float*)d_in[4];
    const float* Bhh  = (const float*)d_in[5];
    const float* Wout = (const float*)d_in[6];
    const float* Bout = (const float*)d_in[7];

    constexpr int B = 2048, T = 1024, H = 20;
    float* Y     = (float*)d_out;            // [1, B*T, 1] flattened
    float* Hlast = Y + (size_t)B * T;        // [1, B, H]

    gru_fused2<<<dim3(B / 2), dim3(64), 0, stream>>>(X, H0, Wih, Whh, Bih, Bhh,
                                                     Wout, Bout, Y, Hlast);
}